// Round 12
// baseline (70090.308 us; speedup 1.0000x reference)
//
#include <hip/hip_runtime.h>
#include <cmath>

namespace {

constexpr int B_ = 8, L_ = 128, IN_ = 64, H_ = 800, C_ = 800, A_ = 128, HD_ = 8;
constexpr int F_ = 870;
constexpr int KX_ = IN_ + C_;          // 864
constexpr int KO_ = HD_ * F_;          // 6960
constexpr double RAD_ = 8.0, BOND_ = 3.8;
constexpr int NB = 256, NT = 512;

// PC geometry: 4 f-slices x 37 col-groups = 148 blocks (bid 100..247)
constexpr int NFS = 4, NCG = 37, NFMX = 218, NCMX = 22;
constexpr int PCN = NFS * NCG;         // 148

// ---- barrier state: first 8 KB of ws (layout as r11) ----
constexpr size_t OF_RES = 2048;                                 // res [B][L][H] f32
constexpr size_t OF_WIT = OF_RES + (size_t)B_ * L_ * H_;        // W_ih^T [2400][864]
constexpr size_t OF_WHT = OF_WIT + (size_t)3 * H_ * KX_;        // W_hh^T [2400][800]
constexpr size_t FLT_END = OF_WHT + (size_t)3 * H_ * H_;        // even
// ---- double region ----
constexpr size_t D_ST  = 0;                                     // state dbuf [2][B][H]
constexpr size_t D_CP  = D_ST + 2ull * B_ * H_;                 // ctx partials [4][B][C]
constexpr size_t D_ANG = D_CP + (size_t)NFS * B_ * C_;          // angles [B][L][3]
constexpr size_t D_POS = D_ANG + (size_t)B_ * L_ * 3;           // positions [B][L][3][3]
constexpr size_t D_DST = D_POS + (size_t)B_ * L_ * 9;           // dist [2][B][L][3] parity
constexpr size_t D_G   = D_DST + 2ull * B_ * L_ * 3;            // G [B][L][A]
constexpr size_t D_W   = D_G + (size_t)B_ * L_ * A_;            // w [B][L][HD]
constexpr size_t D_PCP = D_W + (size_t)B_ * L_ * HD_;           // pooled-part [148][8][8][218]
constexpr size_t D_END = D_PCP + (size_t)PCN * B_ * HD_ * NFMX;
constexpr size_t WS_BYTES = FLT_END * 4 + D_END * 8;            // ~37.4 MB

// One-time init barrier (r11-proven).
__device__ __forceinline__ void gbar_init(unsigned* cnt) {
  __syncthreads();
  const unsigned grp = (unsigned)blockIdx.x >> 5;
  if (threadIdx.x == 0)
    __hip_atomic_fetch_add(&cnt[(25 + grp) * 32], 1u,
                           __ATOMIC_RELEASE, __HIP_MEMORY_SCOPE_AGENT);
  if (blockIdx.x == 0) {
    if (threadIdx.x < 8) {
      while (__hip_atomic_load(&cnt[(25 + threadIdx.x) * 32],
                               __ATOMIC_RELAXED, __HIP_MEMORY_SCOPE_AGENT) < 32u)
        __builtin_amdgcn_s_sleep(8);
    }
    if (threadIdx.x == 0)
      __builtin_amdgcn_fence(__ATOMIC_ACQUIRE, "agent");
    __syncthreads();
    if (threadIdx.x < 8)
      __hip_atomic_store(&cnt[(33 + threadIdx.x) * 32], 1u,
                         __ATOMIC_RELEASE, __HIP_MEMORY_SCOPE_AGENT);
    __syncthreads();
  } else {
    if (threadIdx.x == 0) {
      while (__hip_atomic_load(&cnt[(33 + grp) * 32],
                               __ATOMIC_RELAXED, __HIP_MEMORY_SCOPE_AGENT) < 1u)
        __builtin_amdgcn_s_sleep(8);
      __builtin_amdgcn_fence(__ATOMIC_ACQUIRE, "agent");
    }
    __syncthreads();
  }
}

// Main barrier (r11-proven: elected wbl2 + elected L2-inv per XCD, peers L1-inv).
__device__ __forceinline__ void gbarx(unsigned* cnt, unsigned& ep,
                                      unsigned xcc, unsigned xcnt, unsigned nx) {
  ++ep;
  __syncthreads();
  if (threadIdx.x == 0) {
    const unsigned old = __hip_atomic_fetch_add(&cnt[xcc * 32], 1u,
                             __ATOMIC_RELAXED, __HIP_MEMORY_SCOPE_AGENT);
    if (old == ep * xcnt - 1u) {
      __builtin_amdgcn_fence(__ATOMIC_RELEASE, "agent");
      __hip_atomic_fetch_add(&cnt[512], 1u,
                             __ATOMIC_RELAXED, __HIP_MEMORY_SCOPE_AGENT);
      while (__hip_atomic_load(&cnt[512],
                               __ATOMIC_RELAXED, __HIP_MEMORY_SCOPE_AGENT) < ep * nx)
        __builtin_amdgcn_s_sleep(2);
      __builtin_amdgcn_fence(__ATOMIC_ACQUIRE, "agent");
      __hip_atomic_store(&cnt[(8 + xcc) * 32], ep,
                         __ATOMIC_RELAXED, __HIP_MEMORY_SCOPE_AGENT);
    } else {
      while (__hip_atomic_load(&cnt[(8 + xcc) * 32],
                               __ATOMIC_RELAXED, __HIP_MEMORY_SCOPE_AGENT) < ep)
        __builtin_amdgcn_s_sleep(2);
      asm volatile("buffer_inv sc0\n\ts_waitcnt vmcnt(0)" ::: "memory");
    }
  }
  __syncthreads();
}

__device__ void transp(const float* __restrict__ src, float* __restrict__ dst,
                       int R, int Cn, float* sm) {
  const int tr_ = (R + 31) >> 5, tc_ = (Cn + 31) >> 5;
  for (int t = blockIdx.x; t < tr_ * tc_; t += gridDim.x) {
    const int r0 = (t / tc_) << 5, c0 = (t % tc_) << 5;
    __syncthreads();
    for (int e = threadIdx.x; e < 1024; e += NT) {
      const int rr = e >> 5, cc = e & 31, r = r0 + rr, c = c0 + cc;
      sm[rr * 33 + cc] = (r < R && c < Cn) ? src[(size_t)r * Cn + c] : 0.0f;
    }
    __syncthreads();
    for (int e = threadIdx.x; e < 1024; e += NT) {
      const int cc = e >> 5, rr = e & 31, r = r0 + rr, c = c0 + cc;
      if (r < R && c < Cn) dst[(size_t)c * R + r] = sm[rr * 33 + cc];
    }
  }
}

} // namespace

extern "C" __global__ __launch_bounds__(NT, 1)
void srnn(const float* __restrict__ data, const float* __restrict__ W_ih,
          const float* __restrict__ W_hh, const float* __restrict__ b_ih,
          const float* __restrict__ b_hh, const float* __restrict__ Wa,
          const float* __restrict__ ba, const float* __restrict__ W1,
          const float* __restrict__ b1, const float* __restrict__ W2,
          const float* __restrict__ Wout, const float* __restrict__ bout,
          float* __restrict__ out, float* __restrict__ ws)
{
  // wlds union: GRU blocks (bid<100): 8 neurons x 4992 = 39,936 f32.
  //             PC blocks (100<=bid<248): Wout tile [8][218][nc<=22] = 38,368 f32.
  __shared__ __align__(16) float wlds[39936];    // 159,744 B
  __shared__ double smd[424];                    // 3,392 B (geo needs 408, zs 64)
  __shared__ unsigned s_xcc, s_xcnt, s_nx;
  float* smf = (float*)smd;                      // transp uses wlds as scratch instead
  (void)smf;
  unsigned* cnt = (unsigned*)ws;
  float* res   = ws + OF_RES;
  float* WihT  = ws + OF_WIT;
  float* WhhT  = ws + OF_WHT;
  double* wd   = (double*)(ws + FLT_END);
  double* st2  = wd + D_ST;
  double* cparts = wd + D_CP;                    // [4][B][800]
  double* angD = wd + D_ANG;
  double* posD = wd + D_POS;
  double* dstD = wd + D_DST;                     // [2][B][L][3]
  double* Gd   = wd + D_G;
  double* wAr  = wd + D_W;
  double* pcpA = wd + D_PCP;                     // [148][8][8][218]

  const int bid = blockIdx.x, tid = threadIdx.x;
  const int wid = tid >> 6, lane = tid & 63;
  unsigned ep = 0;

  // ---- XCD discovery (m09) ----
  if (tid == 0) {
    unsigned x;
    asm volatile("s_getreg_b32 %0, hwreg(HW_REG_XCC_ID)" : "=s"(x));
    x &= 7u;
    s_xcc = x;
    __hip_atomic_fetch_add(&cnt[(17 + x) * 32], 1u,
                           __ATOMIC_RELAXED, __HIP_MEMORY_SCOPE_AGENT);
  }

  // ================= init =================
  for (int i = bid * NT + tid; i < (int)(D_ANG - D_ST); i += NB * NT)
    wd[i] = 0.0;                                 // state dbuf + ctx partials = 0
  {
    const int i = bid * NT + tid;                // B*L*A == NB*NT
    const int a = i & (A_ - 1);
    const int bj = i >> 7;
    double acc = (double)b1[a];
    const float* dr = data + (size_t)bj * IN_;
    #pragma unroll 8
    for (int k = 0; k < IN_; ++k)
      acc = fma((double)dr[k], (double)W1[(size_t)(H_ + k) * A_ + a], acc);
    Gd[i] = acc;
  }
  transp(W_ih, WihT, KX_, 3 * H_, wlds);         // wlds as scratch (pre-fill)
  transp(W_hh, WhhT, H_, 3 * H_, wlds);
  gbar_init(cnt);

  // ---- XCD census ----
  if (tid == 0) {
    unsigned n = 0;
    for (int k = 0; k < 8; ++k)
      n += (__hip_atomic_load(&cnt[(17 + k) * 32],
                              __ATOMIC_RELAXED, __HIP_MEMORY_SCOPE_AGENT) > 0u);
    s_nx = n;
    s_xcnt = __hip_atomic_load(&cnt[(17 + s_xcc) * 32],
                               __ATOMIC_RELAXED, __HIP_MEMORY_SCOPE_AGENT);
  }

  // ---- persistent LDS fills ----
  // PC geometry for this block (valid when 100 <= bid < 248)
  const int p  = bid - 100;
  const int fs = (p >= 0 && p < PCN) ? p / NCG : 0;
  const int cg = (p >= 0 && p < PCN) ? p % NCG : 0;
  const int f0 = fs * NFMX, nf = (fs == NFS - 1) ? (F_ - f0) : NFMX;     // 218/216
  const int c0 = cg * NCMX, nc = (cg == NCG - 1) ? (C_ - c0) : NCMX;     // 22/8
  double* pcp = pcpA + (size_t)(p >= 0 ? p : 0) * (B_ * HD_ * NFMX);

  if (bid < 100) {
    for (int rg = 0; rg < 24; ++rg) {            // ih rows: 8 neurons x 3 gates
      const int s = rg / 3, g = rg % 3;
      const int i = bid * 8 + s;
      const float4* src = reinterpret_cast<const float4*>(WihT + (size_t)(g * H_ + i) * KX_);
      float4* dst = reinterpret_cast<float4*>(&wlds[s * 4992 + g * 864]);
      for (int k4 = tid; k4 < 216; k4 += NT) dst[k4] = src[k4];
    }
    for (int rg = 0; rg < 24; ++rg) {            // hh rows
      const int s = rg / 3, g = rg % 3;
      const int i = bid * 8 + s;
      const float4* src = reinterpret_cast<const float4*>(WhhT + (size_t)(g * H_ + i) * H_);
      float4* dst = reinterpret_cast<float4*>(&wlds[s * 4992 + 2592 + g * 800]);
      for (int k4 = tid; k4 < 200; k4 += NT) dst[k4] = src[k4];
    }
  } else if (p < PCN) {
    const int tot = 8 * nf * nc;                 // Wout tile [h][f'][c']
    for (int e = tid; e < tot; e += NT) {
      const int h = e / (nf * nc), r2 = e % (nf * nc);
      const int fp = r2 / nc, cp2 = r2 % nc;
      wlds[(h * NFMX + fp) * nc + cp2] =
          Wout[(size_t)(h * F_ + f0 + fp) * C_ + (c0 + cp2)];
    }
  }
  __syncthreads();
  const unsigned xcc = s_xcc, xcnt = s_xcnt, nx = s_nx;

  // ================= 128 steps, 2 barriers each =================
  for (int idx = 0; idx < L_; ++idx) {
    const int rp = idx & 1;
    const double* sOld = st2 + (size_t)rp * B_ * H_;
    double* sNew = st2 + (size_t)(rp ^ 1) * B_ * H_;
    const double* dstR = dstD + (size_t)(idx & 1) * (B_ * L_ * 3);       // read
    double* dstW = dstD + (size_t)((idx + 1) & 1) * (B_ * L_ * 3);       // write

    // ---- P1: GRU (bid<100, 8 waves) || e/w (bid 100..227) ----
    if (bid < 100) {
      const int i = bid * 8 + wid;               // neuron
      const int b = lane >> 3, ks = lane & 7;
      const float4* wr4 = reinterpret_cast<const float4*>(&wlds[wid * 4992]);
      const float4* wz4 = reinterpret_cast<const float4*>(&wlds[wid * 4992 + 864]);
      const float4* wn4 = reinterpret_cast<const float4*>(&wlds[wid * 4992 + 1728]);
      const float4* dx4 = reinterpret_cast<const float4*>(data + ((size_t)b * L_ + idx) * IN_);
      const double* cpb = cparts + (size_t)b * C_;           // fs stride 6400
      const bool hasb = (idx >= 2);
      double axr = 0., axz = 0., axn = 0.;
      #pragma unroll
      for (int j = 0; j < 2; ++j) {
        const int q = ks + 8 * j;
        const float4 x4 = dx4[q];
        const float4 r4 = wr4[q], z4 = wz4[q], n4 = wn4[q];
        const double x0 = x4.x, x1 = x4.y, x2 = x4.z, x3 = x4.w;
        axr = fma((double)r4.x, x0, axr); axr = fma((double)r4.y, x1, axr);
        axr = fma((double)r4.z, x2, axr); axr = fma((double)r4.w, x3, axr);
        axz = fma((double)z4.x, x0, axz); axz = fma((double)z4.y, x1, axz);
        axz = fma((double)z4.z, x2, axz); axz = fma((double)z4.w, x3, axz);
        axn = fma((double)n4.x, x0, axn); axn = fma((double)n4.y, x1, axn);
        axn = fma((double)n4.z, x2, axn); axn = fma((double)n4.w, x3, axn);
      }
      for (int j = 2; j < 27; ++j) {
        const int q = ks + 8 * j;
        const int e = 4 * q - 64;
        const float4 bt = *reinterpret_cast<const float4*>(bout + e);
        const double* cpe = cpb + e;
        const double x0 = ((cpe[0] + cpe[6400]) + (cpe[12800] + cpe[19200]))
                          + (hasb ? (double)bt.x : 0.0);
        const double x1 = ((cpe[1] + cpe[6401]) + (cpe[12801] + cpe[19201]))
                          + (hasb ? (double)bt.y : 0.0);
        const double x2 = ((cpe[2] + cpe[6402]) + (cpe[12802] + cpe[19202]))
                          + (hasb ? (double)bt.z : 0.0);
        const double x3 = ((cpe[3] + cpe[6403]) + (cpe[12803] + cpe[19203]))
                          + (hasb ? (double)bt.w : 0.0);
        const float4 r4 = wr4[q], z4 = wz4[q], n4 = wn4[q];
        axr = fma((double)r4.x, x0, axr); axr = fma((double)r4.y, x1, axr);
        axr = fma((double)r4.z, x2, axr); axr = fma((double)r4.w, x3, axr);
        axz = fma((double)z4.x, x0, axz); axz = fma((double)z4.y, x1, axz);
        axz = fma((double)z4.z, x2, axz); axz = fma((double)z4.w, x3, axz);
        axn = fma((double)n4.x, x0, axn); axn = fma((double)n4.y, x1, axn);
        axn = fma((double)n4.z, x2, axn); axn = fma((double)n4.w, x3, axn);
      }
      const float4* hr4 = reinterpret_cast<const float4*>(&wlds[wid * 4992 + 2592]);
      const float4* hz4 = reinterpret_cast<const float4*>(&wlds[wid * 4992 + 2592 + 800]);
      const float4* hn4 = reinterpret_cast<const float4*>(&wlds[wid * 4992 + 2592 + 1600]);
      const double* sx = sOld + (size_t)b * H_;
      double ahr = 0., ahz = 0., ahn = 0.;
      for (int j = 0; j < 25; ++j) {
        const int q = ks + 8 * j;
        const int e = 4 * q;
        const double s0 = sx[e], s1 = sx[e + 1], s2 = sx[e + 2], s3 = sx[e + 3];
        const float4 r4 = hr4[q], z4 = hz4[q], n4 = hn4[q];
        ahr = fma((double)r4.x, s0, ahr); ahr = fma((double)r4.y, s1, ahr);
        ahr = fma((double)r4.z, s2, ahr); ahr = fma((double)r4.w, s3, ahr);
        ahz = fma((double)z4.x, s0, ahz); ahz = fma((double)z4.y, s1, ahz);
        ahz = fma((double)z4.z, s2, ahz); ahz = fma((double)z4.w, s3, ahz);
        ahn = fma((double)n4.x, s0, ahn); ahn = fma((double)n4.y, s1, ahn);
        ahn = fma((double)n4.z, s2, ahn); ahn = fma((double)n4.w, s3, ahn);
      }
      #pragma unroll
      for (int off = 1; off < 8; off <<= 1) {
        axr += __shfl_xor(axr, off); axz += __shfl_xor(axz, off); axn += __shfl_xor(axn, off);
        ahr += __shfl_xor(ahr, off); ahz += __shfl_xor(ahz, off); ahn += __shfl_xor(ahn, off);
      }
      if (ks == 0) {
        const double xr = axr + (double)b_ih[i], xz = axz + (double)b_ih[H_ + i],
                     xn = axn + (double)b_ih[2 * H_ + i];
        const double hr = ahr + (double)b_hh[i], hz = ahz + (double)b_hh[H_ + i],
                     hn = ahn + (double)b_hh[2 * H_ + i];
        const double r = 1.0 / (1.0 + exp(-(xr + hr)));
        const double z = 1.0 / (1.0 + exp(-(xz + hz)));
        const double n = tanh(xn + r * hn);
        const double sn = (1.0 - z) * n + z * sOld[b * H_ + i];
        sNew[b * H_ + i] = sn;
        res[((size_t)b * L_ + idx) * H_ + i] = (float)sn;
      }
    } else {
      const int tsk = (bid - 100) * 8 + wid;     // 0..1247; use <1024
      if (tsk < 1024 && idx > 0) {
        const int b = tsk >> 7, j = tsk & (L_ - 1);
        if (j < idx) {
          const size_t bj = (size_t)b * L_ + j;
          double e0 = Gd[bj * A_ + lane], e1 = Gd[bj * A_ + lane + 64];
          const double an0 = angD[bj * 3], an1 = angD[bj * 3 + 1], an2 = angD[bj * 3 + 2];
          const double dd0 = dstR[bj * 3], dd1 = dstR[bj * 3 + 1], dd2 = dstR[bj * 3 + 2];
          e0 = fma((double)W1[864 * A_ + lane], an0, e0);
          e0 = fma((double)W1[865 * A_ + lane], an1, e0);
          e0 = fma((double)W1[866 * A_ + lane], an2, e0);
          e0 = fma((double)W1[867 * A_ + lane], dd0, e0);
          e0 = fma((double)W1[868 * A_ + lane], dd1, e0);
          e0 = fma((double)W1[869 * A_ + lane], dd2, e0);
          e1 = fma((double)W1[864 * A_ + lane + 64], an0, e1);
          e1 = fma((double)W1[865 * A_ + lane + 64], an1, e1);
          e1 = fma((double)W1[866 * A_ + lane + 64], an2, e1);
          e1 = fma((double)W1[867 * A_ + lane + 64], dd0, e1);
          e1 = fma((double)W1[868 * A_ + lane + 64], dd1, e1);
          e1 = fma((double)W1[869 * A_ + lane + 64], dd2, e1);
          e0 = tanh(e0); e1 = tanh(e1);
          double lg[8];
          #pragma unroll
          for (int h = 0; h < 8; ++h) {
            double v = fma(e0, (double)W2[lane * 8 + h], e1 * (double)W2[(lane + 64) * 8 + h]);
            #pragma unroll
            for (int off = 1; off < 64; off <<= 1) v += __shfl_xor(v, off);
            lg[h] = v;
          }
          if (lane == 0) {
            const bool valid = (dd1 <= RAD_);
            double* wrow = wAr + bj * HD_;
            #pragma unroll
            for (int h = 0; h < 8; ++h) wrow[h] = valid ? exp(lg[h]) : 0.0;
          }
        }
      }
    }
    gbarx(cnt, ep, xcc, xcnt, nx);

    // ---- P2: G-upd (0..7) || geo (8) || PC pooled+ctx-partials (100..247) ----
    if (bid < 8) {
      const int b = bid;                         // G-row update, smd-free
      if (tid < 128) {
        const double* sr = sNew + (size_t)b * H_;
        double p2 = 0.0;
        for (int k = 0; k < H_; ++k)
          p2 = fma(sr[k], (double)W1[(size_t)k * A_ + tid], p2);
        Gd[((size_t)b * L_ + idx) * A_ + tid] += p2;
      }
    } else if (bid == 8) {
      // angle = state@Wa+ba; pos row idx; outputs; dist (parity write)
      const int b7 = tid / 48, rem = tid % 48, t3 = rem / 16, ksl = rem & 15;
      if (tid < 384) {
        const double* sr = sNew + (size_t)b7 * H_;
        const int i0 = ksl * 50;
        double p2 = 0.0;
        for (int k = 0; k < 50; ++k)
          p2 = fma(sr[i0 + k], (double)Wa[(i0 + k) * 3 + t3], p2);
        smd[tid] = p2;
      }
      __syncthreads();
      if (tid < 24) {
        const int b2 = tid / 3, t4 = tid % 3;
        double s = (double)ba[t4];
        for (int u = 0; u < 16; ++u) s += smd[b2 * 48 + t4 * 16 + u];
        smd[384 + tid] = s;
        angD[((size_t)b2 * L_ + idx) * 3 + t4] = s;
        out[(size_t)B_ * L_ * 9 + ((size_t)b2 * L_ + idx) * 3 + t4] = (float)s;
      }
      __syncthreads();
      if (tid < 24) {
        const int b2 = tid / 3, t4 = tid % 3;
        const double a = smd[384 + b2 * 3 + t4];
        const double asum = smd[384 + b2 * 3] + smd[384 + b2 * 3 + 1] + smd[384 + b2 * 3 + 2];
        const double sa = sin(a), ca = cos(a), cs = cos(asum), ss = sin(asum);
        double px = 0., py = 0., pz = 0.;
        if (idx > 0) {
          const double* pr = posD + ((size_t)b2 * L_ + idx - 1) * 9 + t4 * 3;
          px = pr[0]; py = pr[1]; pz = pr[2];
        }
        px = fma(BOND_, ca, px);
        py = fma(BOND_, sa * cs, py);
        pz = fma(BOND_, sa * ss, pz);
        double* pw = posD + ((size_t)b2 * L_ + idx) * 9 + t4 * 3;
        pw[0] = px; pw[1] = py; pw[2] = pz;
        float* ow = out + ((size_t)b2 * L_ + idx) * 9 + t4 * 3;
        ow[0] = (float)px; ow[1] = (float)py; ow[2] = (float)pz;
      }
      __syncthreads();
      if (idx < L_ - 1) {
        for (int u = tid; u < 4096; u += NT) {
          const int b = u >> 9, rem2 = u & 511;
          const int j = rem2 >> 2, t6 = rem2 & 3;
          if (t6 < 3 && j <= idx) {
            const double* pa = posD + ((size_t)b * L_ + idx) * 9 + t6 * 3;
            const double* pb = posD + ((size_t)b * L_ + j) * 9 + t6 * 3;
            const double dx = pa[0] - pb[0], dy = pa[1] - pb[1], dz = pa[2] - pb[2];
            dstW[((size_t)b * L_ + j) * 3 + t6] =
                sqrt(fma(dx, dx, fma(dy, dy, fma(dz, dz, 1e-12))));
          }
        }
      }
    } else if (p >= 0 && p < PCN) {
      if (idx >= 1 && idx < L_ - 1) {
        // Stage A: zs per (b,h)
        if (tid < 64) {
          const int b = tid >> 3, h = tid & 7;
          const double* wp = wAr + (size_t)b * L_ * HD_ + h;
          double zs = 0.0;
          for (int j = 0; j < idx; ++j) zs += wp[(size_t)j * HD_];
          smd[tid] = zs;
        }
        __syncthreads();
        // Stage B: pooled-part over this block's f-slice (block-private scratch)
        const int ntask = 64 * nf;
        for (int t = tid; t < ntask; t += NT) {
          const int b = t / (8 * nf);
          const int r2 = t - b * 8 * nf;
          const int h = r2 / nf, fp = r2 - h * nf;
          const int f = f0 + fp;
          const float* fbf = nullptr; const double* fbd = nullptr; int strd = 0;
          if (f < H_)                { fbf = res  + f + (size_t)b * L_ * H_;               strd = H_;  }
          else if (f < H_ + IN_)     { fbf = data + (f - H_) + (size_t)b * L_ * IN_;       strd = IN_; }
          else if (f < H_ + IN_ + 3) { fbd = angD + (f - H_ - IN_) + (size_t)b * L_ * 3;   strd = 3;   }
          else                       { fbd = dstR + (f - H_ - IN_ - 3) + (size_t)b * L_ * 3; strd = 3; }
          const double* wp = wAr + (size_t)b * L_ * HD_ + h;
          double acc = 0.0;
          for (int j = 0; j < idx; ++j) {
            const double fv = fbf ? (double)fbf[(size_t)j * strd] : fbd[(size_t)j * strd];
            acc = fma(wp[(size_t)j * HD_], fv, acc);
          }
          __builtin_nontemporal_store(acc / smd[b * 8 + h],
                                      &pcp[(size_t)(b * 8 + h) * NFMX + fp]);
        }
        asm volatile("s_waitcnt vmcnt(0)" ::: "memory");
        __syncthreads();
        // Stage C: ctx-partial for this (fslice, colgroup)
        for (int t = tid; t < 8 * nc; t += NT) {
          const int b = t / nc, cp2 = t % nc;
          double acc = 0.0;
          for (int h = 0; h < 8; ++h) {
            const double* pr = pcp + (size_t)(b * 8 + h) * NFMX;
            const float* wc = &wlds[(h * NFMX) * nc + cp2];
            for (int fp = 0; fp < nf; ++fp)
              acc = fma(pr[fp], (double)wc[(size_t)fp * nc], acc);
          }
          cparts[((size_t)fs * 8 + b) * C_ + (c0 + cp2)] = acc;
        }
      }
    }
    gbarx(cnt, ep, xcc, xcnt, nx);
  }
}

extern "C" void kernel_launch(void* const* d_in, const int* in_sizes, int n_in,
                              void* d_out, int out_size, void* d_ws, size_t ws_size,
                              hipStream_t stream) {
  (void)in_sizes; (void)n_in; (void)out_size;
  if (ws_size < WS_BYTES) return;
  const float* data = (const float*)d_in[0];
  const float* W_ih = (const float*)d_in[1];
  const float* W_hh = (const float*)d_in[2];
  const float* b_ih = (const float*)d_in[3];
  const float* b_hh = (const float*)d_in[4];
  const float* Wa   = (const float*)d_in[5];
  const float* ba   = (const float*)d_in[6];
  const float* W1   = (const float*)d_in[7];
  const float* b1   = (const float*)d_in[8];
  const float* W2   = (const float*)d_in[9];
  const float* Wout = (const float*)d_in[10];
  const float* bout = (const float*)d_in[11];
  hipMemsetAsync(d_ws, 0, 8192, stream);         // reset barrier state (replay-safe)
  srnn<<<dim3(NB), dim3(NT), 0, stream>>>(data, W_ih, W_hh, b_ih, b_hh, Wa, ba,
                                          W1, b1, W2, Wout, bout,
                                          (float*)d_out, (float*)d_ws);
}

// Round 13
// 10693.859 us; speedup vs baseline: 6.5543x; 6.5543x over previous
//
#include <hip/hip_runtime.h>
#include <cmath>

namespace {

constexpr int B_ = 8, L_ = 128, IN_ = 64, H_ = 800, C_ = 800, A_ = 128, HD_ = 8;
constexpr int F_ = 870;
constexpr int KX_ = IN_ + C_;          // 864
constexpr int KO_ = HD_ * F_;          // 6960
constexpr double RAD_ = 8.0, BOND_ = 3.8;
constexpr int NB = 256, NT = 512;

// ---- barrier state: first 8 KB of ws (layout as r11) ----
constexpr size_t OF_RES = 2048;                                 // res [B][L][H] f32
constexpr size_t OF_WIT = OF_RES + (size_t)B_ * L_ * H_;        // W_ih^T [2400][864]
constexpr size_t OF_WHT = OF_WIT + (size_t)3 * H_ * KX_;        // W_hh^T [2400][800]
constexpr size_t OF_WOT = OF_WHT + (size_t)3 * H_ * H_;         // Wout^T [800][6960]
constexpr size_t FLT_END = OF_WOT + (size_t)C_ * KO_;           // even
// ---- double region ----
constexpr size_t D_ST  = 0;                                     // state dbuf [2][B][H]
constexpr size_t D_CTX = D_ST + 2ull * B_ * H_;                 // context [B][C]
constexpr size_t D_ANG = D_CTX + (size_t)B_ * C_;               // angles [B][L][3]
constexpr size_t D_POS = D_ANG + (size_t)B_ * L_ * 3;           // positions [B][L][3][3]
constexpr size_t D_DST = D_POS + (size_t)B_ * L_ * 9;           // dist [2][B][L][3] parity
constexpr size_t D_G   = D_DST + 2ull * B_ * L_ * 3;            // G [B][L][A]
constexpr size_t D_W   = D_G + (size_t)B_ * L_ * A_;            // w [B][L][HD]
constexpr size_t D_WT  = D_W + (size_t)B_ * L_ * HD_;           // wT [B][HD][L]
constexpr size_t D_PN  = D_WT + (size_t)B_ * HD_ * L_;          // pooledN [B][KO]
constexpr size_t D_END = D_PN + (size_t)B_ * KO_;
constexpr size_t WS_BYTES = FLT_END * 4 + D_END * 8;            // ~43.5 MB

// LDS geometry (floats). Type-A (bid<160): 5 neurons + 2 Wout cols.
// Type-B (bid>=160): 5 Wout cols.
constexpr int LD_NEUR = 4992;          // per-neuron: 3*864 ih + 3*800 hh
constexpr int LD_WOUT_A = 24960;       // type-A Wout base (5*4992)
constexpr int LD_TOT = 38880;          // 155,520 B

// One-time init barrier (r11-proven).
__device__ __forceinline__ void gbar_init(unsigned* cnt) {
  __syncthreads();
  const unsigned grp = (unsigned)blockIdx.x >> 5;
  if (threadIdx.x == 0)
    __hip_atomic_fetch_add(&cnt[(25 + grp) * 32], 1u,
                           __ATOMIC_RELEASE, __HIP_MEMORY_SCOPE_AGENT);
  if (blockIdx.x == 0) {
    if (threadIdx.x < 8) {
      while (__hip_atomic_load(&cnt[(25 + threadIdx.x) * 32],
                               __ATOMIC_RELAXED, __HIP_MEMORY_SCOPE_AGENT) < 32u)
        __builtin_amdgcn_s_sleep(8);
    }
    if (threadIdx.x == 0)
      __builtin_amdgcn_fence(__ATOMIC_ACQUIRE, "agent");
    __syncthreads();
    if (threadIdx.x < 8)
      __hip_atomic_store(&cnt[(33 + threadIdx.x) * 32], 1u,
                         __ATOMIC_RELEASE, __HIP_MEMORY_SCOPE_AGENT);
    __syncthreads();
  } else {
    if (threadIdx.x == 0) {
      while (__hip_atomic_load(&cnt[(33 + grp) * 32],
                               __ATOMIC_RELAXED, __HIP_MEMORY_SCOPE_AGENT) < 1u)
        __builtin_amdgcn_s_sleep(8);
      __builtin_amdgcn_fence(__ATOMIC_ACQUIRE, "agent");
    }
    __syncthreads();
  }
}

// Main barrier (r11-proven: elected wbl2 + elected L2-inv per XCD, peers L1-inv).
__device__ __forceinline__ void gbarx(unsigned* cnt, unsigned& ep,
                                      unsigned xcc, unsigned xcnt, unsigned nx) {
  ++ep;
  __syncthreads();
  if (threadIdx.x == 0) {
    const unsigned old = __hip_atomic_fetch_add(&cnt[xcc * 32], 1u,
                             __ATOMIC_RELAXED, __HIP_MEMORY_SCOPE_AGENT);
    if (old == ep * xcnt - 1u) {
      __builtin_amdgcn_fence(__ATOMIC_RELEASE, "agent");
      __hip_atomic_fetch_add(&cnt[512], 1u,
                             __ATOMIC_RELAXED, __HIP_MEMORY_SCOPE_AGENT);
      while (__hip_atomic_load(&cnt[512],
                               __ATOMIC_RELAXED, __HIP_MEMORY_SCOPE_AGENT) < ep * nx)
        __builtin_amdgcn_s_sleep(2);
      __builtin_amdgcn_fence(__ATOMIC_ACQUIRE, "agent");
      __hip_atomic_store(&cnt[(8 + xcc) * 32], ep,
                         __ATOMIC_RELAXED, __HIP_MEMORY_SCOPE_AGENT);
    } else {
      while (__hip_atomic_load(&cnt[(8 + xcc) * 32],
                               __ATOMIC_RELAXED, __HIP_MEMORY_SCOPE_AGENT) < ep)
        __builtin_amdgcn_s_sleep(2);
      asm volatile("buffer_inv sc0\n\ts_waitcnt vmcnt(0)" ::: "memory");
    }
  }
  __syncthreads();
}

__device__ void transp(const float* __restrict__ src, float* __restrict__ dst,
                       int R, int Cn, float* sm) {
  const int tr_ = (R + 31) >> 5, tc_ = (Cn + 31) >> 5;
  for (int t = blockIdx.x; t < tr_ * tc_; t += gridDim.x) {
    const int r0 = (t / tc_) << 5, c0 = (t % tc_) << 5;
    __syncthreads();
    for (int e = threadIdx.x; e < 1024; e += NT) {
      const int rr = e >> 5, cc = e & 31, r = r0 + rr, c = c0 + cc;
      sm[rr * 33 + cc] = (r < R && c < Cn) ? src[(size_t)r * Cn + c] : 0.0f;
    }
    __syncthreads();
    for (int e = threadIdx.x; e < 1024; e += NT) {
      const int cc = e >> 5, rr = e & 31, r = r0 + rr, c = c0 + cc;
      if (r < R && c < Cn) dst[(size_t)c * R + r] = sm[rr * 33 + cc];
    }
  }
}

} // namespace

extern "C" __global__ __launch_bounds__(NT, 1)
void srnn(const float* __restrict__ data, const float* __restrict__ W_ih,
          const float* __restrict__ W_hh, const float* __restrict__ b_ih,
          const float* __restrict__ b_hh, const float* __restrict__ Wa,
          const float* __restrict__ ba, const float* __restrict__ W1,
          const float* __restrict__ b1, const float* __restrict__ W2,
          const float* __restrict__ Wout, const float* __restrict__ bout,
          float* __restrict__ out, float* __restrict__ ws)
{
  __shared__ __align__(16) float wlds[LD_TOT];   // 155,520 B persistent weights
  __shared__ double smd[528];                    // 4,224 B scratch (1056 floats)
  __shared__ unsigned s_xcc, s_xcnt, s_nx;
  float* smf = (float*)smd;
  unsigned* cnt = (unsigned*)ws;
  float* res   = ws + OF_RES;
  float* WihT  = ws + OF_WIT;
  float* WhhT  = ws + OF_WHT;
  float* WoutT = ws + OF_WOT;
  double* wd   = (double*)(ws + FLT_END);
  double* st2  = wd + D_ST;
  double* ctxD = wd + D_CTX;
  double* angD = wd + D_ANG;
  double* posD = wd + D_POS;
  double* dstD = wd + D_DST;                     // [2][B][L][3]
  double* Gd   = wd + D_G;
  double* wAr  = wd + D_W;
  double* wT   = wd + D_WT;                      // [B][HD][L]
  double* pND  = wd + D_PN;

  const int bid = blockIdx.x, tid = threadIdx.x;
  const int wid = tid >> 6, lane = tid & 63;
  unsigned ep = 0;

  // ---- XCD discovery (m09) ----
  if (tid == 0) {
    unsigned x;
    asm volatile("s_getreg_b32 %0, hwreg(HW_REG_XCC_ID)" : "=s"(x));
    x &= 7u;
    s_xcc = x;
    __hip_atomic_fetch_add(&cnt[(17 + x) * 32], 1u,
                           __ATOMIC_RELAXED, __HIP_MEMORY_SCOPE_AGENT);
  }

  // ================= init (covered by fenced gbar_init) =================
  for (int i = bid * NT + tid; i < (int)(D_ANG - D_ST); i += NB * NT)
    wd[i] = 0.0;                                 // state dbuf + ctx = 0
  {
    const int i = bid * NT + tid;                // B*L*A == NB*NT
    const int a = i & (A_ - 1);
    const int bj = i >> 7;
    double acc = (double)b1[a];
    const float* dr = data + (size_t)bj * IN_;
    #pragma unroll 8
    for (int k = 0; k < IN_; ++k)
      acc = fma((double)dr[k], (double)W1[(size_t)(H_ + k) * A_ + a], acc);
    Gd[i] = acc;
  }
  transp(W_ih, WihT, KX_, 3 * H_, smf);          // coalesced staging (r4-proven)
  transp(W_hh, WhhT, H_, 3 * H_, smf);
  transp(Wout, WoutT, KO_, C_, smf);
  gbar_init(cnt);

  // ---- XCD census ----
  if (tid == 0) {
    unsigned n = 0;
    for (int k = 0; k < 8; ++k)
      n += (__hip_atomic_load(&cnt[(17 + k) * 32],
                              __ATOMIC_RELAXED, __HIP_MEMORY_SCOPE_AGENT) > 0u);
    s_nx = n;
    s_xcnt = __hip_atomic_load(&cnt[(17 + s_xcc) * 32],
                               __ATOMIC_RELAXED, __HIP_MEMORY_SCOPE_AGENT);
  }

  // ---- persistent LDS weight slices (coalesced float4 from transposed) ----
  if (bid < 160) {
    for (int rg = 0; rg < 15; ++rg) {            // ih rows: 5 neurons x 3 gates
      const int s = rg / 3, g = rg % 3;
      const int i = bid * 5 + s;
      const float4* src = reinterpret_cast<const float4*>(WihT + (size_t)(g * H_ + i) * KX_);
      float4* dst = reinterpret_cast<float4*>(&wlds[s * LD_NEUR + g * 864]);
      for (int k4 = tid; k4 < 216; k4 += NT) dst[k4] = src[k4];
    }
    for (int rg = 0; rg < 15; ++rg) {            // hh rows
      const int s = rg / 3, g = rg % 3;
      const int i = bid * 5 + s;
      const float4* src = reinterpret_cast<const float4*>(WhhT + (size_t)(g * H_ + i) * H_);
      float4* dst = reinterpret_cast<float4*>(&wlds[s * LD_NEUR + 2592 + g * 800]);
      for (int k4 = tid; k4 < 200; k4 += NT) dst[k4] = src[k4];
    }
    for (int cs = 0; cs < 2; ++cs) {             // 2 Wout cols
      const int c = bid * 2 + cs;
      const float4* src = reinterpret_cast<const float4*>(WoutT + (size_t)c * KO_);
      float4* dst = reinterpret_cast<float4*>(&wlds[LD_WOUT_A + cs * KO_]);
      for (int k4 = tid; k4 < 1740; k4 += NT) dst[k4] = src[k4];
    }
  } else {
    for (int cs = 0; cs < 5; ++cs) {             // 5 Wout cols
      const int c = 320 + (bid - 160) * 5 + cs;
      const float4* src = reinterpret_cast<const float4*>(WoutT + (size_t)c * KO_);
      float4* dst = reinterpret_cast<float4*>(&wlds[cs * KO_]);
      for (int k4 = tid; k4 < 1740; k4 += NT) dst[k4] = src[k4];
    }
  }
  __syncthreads();
  const unsigned xcc = s_xcc, xcnt = s_xcnt, nx = s_nx;

  // ================= 128 steps, 3 barriers each =================
  for (int idx = 0; idx < L_; ++idx) {
    const int rp = idx & 1;
    const double* sOld = st2 + (size_t)rp * B_ * H_;
    double* sNew = st2 + (size_t)(rp ^ 1) * B_ * H_;
    const double* dstR = dstD + (size_t)(idx & 1) * (B_ * L_ * 3);       // read
    double* dstW = dstD + (size_t)((idx + 1) & 1) * (B_ * L_ * 3);       // write

    // ---- P1: GRU (type-A waves 0..4) || e/logits/w (1024 waves) ----
    if (bid < 160 && wid < 5) {
      const int i = bid * 5 + wid;               // neuron
      const int b = lane >> 3, ks = lane & 7;
      const float4* wr4 = reinterpret_cast<const float4*>(&wlds[wid * LD_NEUR]);
      const float4* wz4 = reinterpret_cast<const float4*>(&wlds[wid * LD_NEUR + 864]);
      const float4* wn4 = reinterpret_cast<const float4*>(&wlds[wid * LD_NEUR + 1728]);
      const float4* dx4 = reinterpret_cast<const float4*>(data + ((size_t)b * L_ + idx) * IN_);
      const double* cx = ctxD + (size_t)b * C_;
      double axr = 0., axz = 0., axn = 0.;
      #pragma unroll
      for (int j = 0; j < 2; ++j) {
        const int q = ks + 8 * j;
        const float4 x4 = dx4[q];
        const float4 r4 = wr4[q], z4 = wz4[q], n4 = wn4[q];
        const double x0 = x4.x, x1 = x4.y, x2 = x4.z, x3 = x4.w;
        axr = fma((double)r4.x, x0, axr); axr = fma((double)r4.y, x1, axr);
        axr = fma((double)r4.z, x2, axr); axr = fma((double)r4.w, x3, axr);
        axz = fma((double)z4.x, x0, axz); axz = fma((double)z4.y, x1, axz);
        axz = fma((double)z4.z, x2, axz); axz = fma((double)z4.w, x3, axz);
        axn = fma((double)n4.x, x0, axn); axn = fma((double)n4.y, x1, axn);
        axn = fma((double)n4.z, x2, axn); axn = fma((double)n4.w, x3, axn);
      }
      #pragma unroll 5
      for (int j = 2; j < 27; ++j) {
        const int q = ks + 8 * j;
        const int e = 4 * q - 64;
        const double x0 = cx[e], x1 = cx[e + 1], x2 = cx[e + 2], x3 = cx[e + 3];
        const float4 r4 = wr4[q], z4 = wz4[q], n4 = wn4[q];
        axr = fma((double)r4.x, x0, axr); axr = fma((double)r4.y, x1, axr);
        axr = fma((double)r4.z, x2, axr); axr = fma((double)r4.w, x3, axr);
        axz = fma((double)z4.x, x0, axz); axz = fma((double)z4.y, x1, axz);
        axz = fma((double)z4.z, x2, axz); axz = fma((double)z4.w, x3, axz);
        axn = fma((double)n4.x, x0, axn); axn = fma((double)n4.y, x1, axn);
        axn = fma((double)n4.z, x2, axn); axn = fma((double)n4.w, x3, axn);
      }
      const float4* hr4 = reinterpret_cast<const float4*>(&wlds[wid * LD_NEUR + 2592]);
      const float4* hz4 = reinterpret_cast<const float4*>(&wlds[wid * LD_NEUR + 2592 + 800]);
      const float4* hn4 = reinterpret_cast<const float4*>(&wlds[wid * LD_NEUR + 2592 + 1600]);
      const double* sx = sOld + (size_t)b * H_;
      double ahr = 0., ahz = 0., ahn = 0.;
      #pragma unroll 5
      for (int j = 0; j < 25; ++j) {
        const int q = ks + 8 * j;
        const int e = 4 * q;
        const double s0 = sx[e], s1 = sx[e + 1], s2 = sx[e + 2], s3 = sx[e + 3];
        const float4 r4 = hr4[q], z4 = hz4[q], n4 = hn4[q];
        ahr = fma((double)r4.x, s0, ahr); ahr = fma((double)r4.y, s1, ahr);
        ahr = fma((double)r4.z, s2, ahr); ahr = fma((double)r4.w, s3, ahr);
        ahz = fma((double)z4.x, s0, ahz); ahz = fma((double)z4.y, s1, ahz);
        ahz = fma((double)z4.z, s2, ahz); ahz = fma((double)z4.w, s3, ahz);
        ahn = fma((double)n4.x, s0, ahn); ahn = fma((double)n4.y, s1, ahn);
        ahn = fma((double)n4.z, s2, ahn); ahn = fma((double)n4.w, s3, ahn);
      }
      #pragma unroll
      for (int off = 1; off < 8; off <<= 1) {
        axr += __shfl_xor(axr, off); axz += __shfl_xor(axz, off); axn += __shfl_xor(axn, off);
        ahr += __shfl_xor(ahr, off); ahz += __shfl_xor(ahz, off); ahn += __shfl_xor(ahn, off);
      }
      if (ks == 0) {
        const double xr = axr + (double)b_ih[i], xz = axz + (double)b_ih[H_ + i],
                     xn = axn + (double)b_ih[2 * H_ + i];
        const double hr = ahr + (double)b_hh[i], hz = ahz + (double)b_hh[H_ + i],
                     hn = ahn + (double)b_hh[2 * H_ + i];
        const double r = 1.0 / (1.0 + exp(-(xr + hr)));
        const double z = 1.0 / (1.0 + exp(-(xz + hz)));
        const double n = tanh(xn + r * hn);
        const double sn = (1.0 - z) * n + z * sOld[b * H_ + i];
        sNew[b * H_ + i] = sn;
        res[((size_t)b * L_ + idx) * H_ + i] = (float)sn;
      }
    } else {
      int tsk = -1;
      if (bid >= 160) tsk = (bid - 160) * 8 + wid;          // 0..767
      else tsk = 768 + bid * 3 + (wid - 5);                  // 768..1247
      if (tsk < 1024 && idx > 0) {
        const int b = tsk >> 7, j = tsk & (L_ - 1);
        if (j < idx) {                           // guard: skip future rows
          const size_t bj = (size_t)b * L_ + j;
          double e0 = Gd[bj * A_ + lane], e1 = Gd[bj * A_ + lane + 64];
          const double an0 = angD[bj * 3], an1 = angD[bj * 3 + 1], an2 = angD[bj * 3 + 2];
          const double dd0 = dstR[bj * 3], dd1 = dstR[bj * 3 + 1], dd2 = dstR[bj * 3 + 2];
          e0 = fma((double)W1[864 * A_ + lane], an0, e0);
          e0 = fma((double)W1[865 * A_ + lane], an1, e0);
          e0 = fma((double)W1[866 * A_ + lane], an2, e0);
          e0 = fma((double)W1[867 * A_ + lane], dd0, e0);
          e0 = fma((double)W1[868 * A_ + lane], dd1, e0);
          e0 = fma((double)W1[869 * A_ + lane], dd2, e0);
          e1 = fma((double)W1[864 * A_ + lane + 64], an0, e1);
          e1 = fma((double)W1[865 * A_ + lane + 64], an1, e1);
          e1 = fma((double)W1[866 * A_ + lane + 64], an2, e1);
          e1 = fma((double)W1[867 * A_ + lane + 64], dd0, e1);
          e1 = fma((double)W1[868 * A_ + lane + 64], dd1, e1);
          e1 = fma((double)W1[869 * A_ + lane + 64], dd2, e1);
          e0 = tanh(e0); e1 = tanh(e1);
          double lg[8];
          #pragma unroll
          for (int h = 0; h < 8; ++h) {
            double v = fma(e0, (double)W2[lane * 8 + h], e1 * (double)W2[(lane + 64) * 8 + h]);
            #pragma unroll
            for (int off = 1; off < 64; off <<= 1) v += __shfl_xor(v, off);
            lg[h] = v;
          }
          if (lane == 0) {
            const bool valid = (dd1 <= RAD_);
            double* wrow = wAr + bj * HD_;
            #pragma unroll
            for (int h = 0; h < 8; ++h) {
              const double wv = valid ? exp(lg[h]) : 0.0;
              wrow[h] = wv;
              wT[((size_t)b * HD_ + h) * L_ + j] = wv;   // transposed copy
            }
          }
        }
      }
    }
    gbarx(cnt, ep, xcc, xcnt, nx);

    // ---- P2: pooled (0..127) || G-update (128..135) || angle+pos+dist (136) ----
    if (bid < 128) {
      if (idx > 0) {
        const int b = bid >> 4, sl = bid & 15;
        if (tid < 8) {                           // zs per h, same order as before
          const double* wt = wT + ((size_t)b * HD_ + tid) * L_;
          double zs = 0.0;
          for (int j = 0; j < idx; ++j) zs += wt[j];
          smd[tid] = zs;
        }
        __syncthreads();
        const int f0 = sl * 55;
        const int fn = (F_ - f0 < 55) ? (F_ - f0) : 55;
        const int fl = tid >> 3, h = tid & 7;
        if (fl < fn) {
          const int f = f0 + fl;
          const float* fbf = nullptr; const double* fbd = nullptr; int strd = 0;
          if (f < H_)                { fbf = res  + f + (size_t)b * L_ * H_;               strd = H_;  }
          else if (f < H_ + IN_)     { fbf = data + (f - H_) + (size_t)b * L_ * IN_;       strd = IN_; }
          else if (f < H_ + IN_ + 3) { fbd = angD + (f - H_ - IN_) + (size_t)b * L_ * 3;   strd = 3;   }
          else                       { fbd = dstR + (f - H_ - IN_ - 3) + (size_t)b * L_ * 3; strd = 3; }
          const double* wt = wT + ((size_t)b * HD_ + h) * L_;
          double acc = 0.0;
          #pragma unroll 4
          for (int j = 0; j < idx; ++j) {
            const double fv = fbf ? (double)fbf[(size_t)j * strd] : fbd[(size_t)j * strd];
            acc = fma(wt[j], fv, acc);
          }
          pND[(size_t)b * KO_ + (size_t)h * F_ + f] = acc / smd[h];
        }
      }
    } else if (bid < 136) {
      const int b = bid - 128;                   // G-row update for step idx
      const int a = tid & (A_ - 1), ksl = tid >> 7;
      const double* sr = sNew + (size_t)b * H_;
      const int i0 = ksl * 200;
      double p = 0.0;
      #pragma unroll 4
      for (int k = 0; k < 200; ++k)
        p = fma(sr[i0 + k], (double)W1[(size_t)(i0 + k) * A_ + a], p);
      smd[tid] = p;
      __syncthreads();
      if (tid < 128)
        Gd[((size_t)b * L_ + idx) * A_ + tid] +=
            smd[tid] + smd[128 + tid] + smd[256 + tid] + smd[384 + tid];
    } else if (bid == 136) {
      const int b7 = tid / 48, rem = tid % 48, t3 = rem / 16, ksl = rem & 15;
      if (tid < 384) {
        const double* sr = sNew + (size_t)b7 * H_;
        const int i0 = ksl * 50;
        double p = 0.0;
        for (int k = 0; k < 50; ++k)
          p = fma(sr[i0 + k], (double)Wa[(i0 + k) * 3 + t3], p);
        smd[tid] = p;
      }
      __syncthreads();
      if (tid < 24) {
        const int b2 = tid / 3, t4 = tid % 3;
        double s = (double)ba[t4];
        for (int u = 0; u < 16; ++u) s += smd[b2 * 48 + t4 * 16 + u];
        smd[384 + tid] = s;
        angD[((size_t)b2 * L_ + idx) * 3 + t4] = s;
        out[(size_t)B_ * L_ * 9 + ((size_t)b2 * L_ + idx) * 3 + t4] = (float)s;
      }
      __syncthreads();
      if (tid < 24) {
        const int b2 = tid / 3, t4 = tid % 3;
        const double a = smd[384 + b2 * 3 + t4];
        const double asum = smd[384 + b2 * 3] + smd[384 + b2 * 3 + 1] + smd[384 + b2 * 3 + 2];
        const double sa = sin(a), ca = cos(a), cs = cos(asum), ss = sin(asum);
        double px = 0., py = 0., pz = 0.;
        if (idx > 0) {
          const double* pr = posD + ((size_t)b2 * L_ + idx - 1) * 9 + t4 * 3;
          px = pr[0]; py = pr[1]; pz = pr[2];
        }
        px = fma(BOND_, ca, px);
        py = fma(BOND_, sa * cs, py);
        pz = fma(BOND_, sa * ss, pz);
        double* pw = posD + ((size_t)b2 * L_ + idx) * 9 + t4 * 3;
        pw[0] = px; pw[1] = py; pw[2] = pz;
        float* ow = out + ((size_t)b2 * L_ + idx) * 9 + t4 * 3;
        ow[0] = (float)px; ow[1] = (float)py; ow[2] = (float)pz;
      }
      __syncthreads();
      if (idx < L_ - 1) {                        // dist rows j<=idx vs pos[idx]
        for (int u = tid; u < 4096; u += NT) {
          const int b = u >> 9, rem2 = u & 511;
          const int j = rem2 >> 2, t6 = rem2 & 3;
          if (t6 < 3 && j <= idx) {
            const double* pa = posD + ((size_t)b * L_ + idx) * 9 + t6 * 3;
            const double* pb = posD + ((size_t)b * L_ + j) * 9 + t6 * 3;
            const double dx = pa[0] - pb[0], dy = pa[1] - pb[1], dz = pa[2] - pb[2];
            dstW[((size_t)b * L_ + j) * 3 + t6] =
                sqrt(fma(dx, dx, fma(dy, dy, fma(dz, dz, 1e-12))));
          }
        }
      }
    }
    gbarx(cnt, ep, xcc, xcnt, nx);

    // ---- P3: ctx = pooledN @ Wout(LDS cols) + bout ----
    if (idx < L_ - 1) {
      const int ntask = (bid < 160) ? 2 : 5;
      for (int u = 0; u < ntask; ++u) {
        const int t = wid + 8 * u;
        const int cs = t >> 3, b = t & 7;
        const int c = (bid < 160) ? (bid * 2 + cs) : (320 + (bid - 160) * 5 + cs);
        const int cbase = ((bid < 160) ? LD_WOUT_A : 0) + cs * KO_;
        double acc = 0.0;
        if (idx > 0) {
          const double* pr = pND + (size_t)b * KO_;
          #pragma unroll 4
          for (int m = 0; m < 27; ++m) {         // q max 1727 < 1740: no guard
            const int q = lane + 64 * m;
            const float4 w4 = *reinterpret_cast<const float4*>(&wlds[cbase + 4 * q]);
            const int e = 4 * q;
            acc = fma((double)w4.x, pr[e],     acc);
            acc = fma((double)w4.y, pr[e + 1], acc);
            acc = fma((double)w4.z, pr[e + 2], acc);
            acc = fma((double)w4.w, pr[e + 3], acc);
          }
          {                                       // m = 27, guarded tail
            const int q = lane + 64 * 27;
            if (q < 1740) {
              const float4 w4 = *reinterpret_cast<const float4*>(&wlds[cbase + 4 * q]);
              const int e = 4 * q;
              acc = fma((double)w4.x, pr[e],     acc);
              acc = fma((double)w4.y, pr[e + 1], acc);
              acc = fma((double)w4.z, pr[e + 2], acc);
              acc = fma((double)w4.w, pr[e + 3], acc);
            }
          }
          #pragma unroll
          for (int off = 1; off < 64; off <<= 1) acc += __shfl_xor(acc, off);
        }
        if (lane == 0)
          ctxD[b * C_ + c] = (idx > 0) ? (acc + (double)bout[c]) : 0.0;
      }
    }
    gbarx(cnt, ep, xcc, xcnt, nx);
  }
}

extern "C" void kernel_launch(void* const* d_in, const int* in_sizes, int n_in,
                              void* d_out, int out_size, void* d_ws, size_t ws_size,
                              hipStream_t stream) {
  (void)in_sizes; (void)n_in; (void)out_size;
  if (ws_size < WS_BYTES) return;
  const float* data = (const float*)d_in[0];
  const float* W_ih = (const float*)d_in[1];
  const float* W_hh = (const float*)d_in[2];
  const float* b_ih = (const float*)d_in[3];
  const float* b_hh = (const float*)d_in[4];
  const float* Wa   = (const float*)d_in[5];
  const float* ba   = (const float*)d_in[6];
  const float* W1   = (const float*)d_in[7];
  const float* b1   = (const float*)d_in[8];
  const float* W2   = (const float*)d_in[9];
  const float* Wout = (const float*)d_in[10];
  const float* bout = (const float*)d_in[11];
  hipMemsetAsync(d_ws, 0, 8192, stream);         // reset barrier state (replay-safe)
  srnn<<<dim3(NB), dim3(NT), 0, stream>>>(data, W_ih, W_hh, b_ih, b_hh, Wa, ba,
                                          W1, b1, W2, Wout, bout,
                                          (float*)d_out, (float*)d_ws);
}

// Round 15
// 10640.821 us; speedup vs baseline: 6.5869x; 1.0050x over previous
//
#include <hip/hip_runtime.h>
#include <cmath>

namespace {

constexpr int B_ = 8, L_ = 128, IN_ = 64, H_ = 800, C_ = 800, A_ = 128, HD_ = 8;
constexpr int F_ = 870;
constexpr int KX_ = IN_ + C_;          // 864
constexpr int KO_ = HD_ * F_;          // 6960
constexpr double RAD_ = 8.0, BOND_ = 3.8;
constexpr int NB = 256, NT = 512;

// ---- barrier state: first 8 KB of ws ----
constexpr size_t OF_RES = 2048;                                 // res [B][L][H] f32
constexpr size_t OF_WIT = OF_RES + (size_t)B_ * L_ * H_;        // W_ih^T [2400][864]
constexpr size_t OF_WHT = OF_WIT + (size_t)3 * H_ * KX_;        // W_hh^T [2400][800]
constexpr size_t OF_WOT = OF_WHT + (size_t)3 * H_ * H_;         // Wout^T [800][6960]
constexpr size_t FLT_END = OF_WOT + (size_t)C_ * KO_;           // even
// ---- double region ----
constexpr size_t D_ST  = 0;                                     // state dbuf [2][B][H]
constexpr size_t D_CTX = D_ST + 2ull * B_ * H_;                 // context [B][C]
constexpr size_t D_ANG = D_CTX + (size_t)B_ * C_;               // angles [B][L][3]
constexpr size_t D_POS = D_ANG + (size_t)B_ * L_ * 3;           // positions [B][L][3][3]
constexpr size_t D_DST = D_POS + (size_t)B_ * L_ * 9;           // dist [2][B][L][3] parity
constexpr size_t D_G   = D_DST + 2ull * B_ * L_ * 3;            // G [B][L][A]
constexpr size_t D_W   = D_G + (size_t)B_ * L_ * A_;            // w [B][L][HD]
constexpr size_t D_WT  = D_W + (size_t)B_ * L_ * HD_;           // wT [B][HD][L]
constexpr size_t D_PN  = D_WT + (size_t)B_ * HD_ * L_;          // pooledN [B][KO]
constexpr size_t D_END = D_PN + (size_t)B_ * KO_;
constexpr size_t WS_BYTES = FLT_END * 4 + D_END * 8;            // ~43.5 MB

// LDS geometry (floats). Type-A (bid<160): 5 neurons + 2 Wout cols.
// Type-B (bid>=160): 5 Wout cols.
constexpr int LD_NEUR = 4992;          // per-neuron: 3*864 ih + 3*800 hh
constexpr int LD_WOUT_A = 24960;       // type-A Wout base (5*4992)
constexpr int LD_TOT = 38880;          // 155,520 B

// One-time init barrier (agent-scope; r11/r13-proven).
// PITFALL (r14): workgroup-scope global atomics are NOT usable for
// inter-block signaling -- poll loads may be serviced from the CU's L1
// forever (livelock). All polls here are agent-scope.
__device__ __forceinline__ void gbar_init(unsigned* cnt) {
  __syncthreads();
  const unsigned grp = (unsigned)blockIdx.x >> 5;
  if (threadIdx.x == 0)
    __hip_atomic_fetch_add(&cnt[(25 + grp) * 32], 1u,
                           __ATOMIC_RELEASE, __HIP_MEMORY_SCOPE_AGENT);
  if (blockIdx.x == 0) {
    if (threadIdx.x < 8) {
      while (__hip_atomic_load(&cnt[(25 + threadIdx.x) * 32],
                               __ATOMIC_RELAXED, __HIP_MEMORY_SCOPE_AGENT) < 32u)
        __builtin_amdgcn_s_sleep(8);
    }
    if (threadIdx.x == 0)
      __builtin_amdgcn_fence(__ATOMIC_ACQUIRE, "agent");
    __syncthreads();
    if (threadIdx.x < 8)
      __hip_atomic_store(&cnt[(33 + threadIdx.x) * 32], 1u,
                         __ATOMIC_RELEASE, __HIP_MEMORY_SCOPE_AGENT);
    __syncthreads();
  } else {
    if (threadIdx.x == 0) {
      while (__hip_atomic_load(&cnt[(33 + grp) * 32],
                               __ATOMIC_RELAXED, __HIP_MEMORY_SCOPE_AGENT) < 1u)
        __builtin_amdgcn_s_sleep(8);
      __builtin_amdgcn_fence(__ATOMIC_ACQUIRE, "agent");
    }
    __syncthreads();
  }
}

// Main barrier (r11/r13-proven): elected wbl2 + elected L2-inv per XCD,
// peers flash their CU's L1 only. All counters/flags agent-scope relaxed.
__device__ __forceinline__ void gbarx(unsigned* cnt, unsigned& ep,
                                      unsigned xcc, unsigned xcnt, unsigned nx) {
  ++ep;
  __syncthreads();
  if (threadIdx.x == 0) {
    const unsigned old = __hip_atomic_fetch_add(&cnt[xcc * 32], 1u,
                             __ATOMIC_RELAXED, __HIP_MEMORY_SCOPE_AGENT);
    if (old == ep * xcnt - 1u) {                 // last arriver on this XCD
      __builtin_amdgcn_fence(__ATOMIC_RELEASE, "agent");   // ONE wbl2 / XCD
      __hip_atomic_fetch_add(&cnt[512], 1u,
                             __ATOMIC_RELAXED, __HIP_MEMORY_SCOPE_AGENT);
      while (__hip_atomic_load(&cnt[512],
                               __ATOMIC_RELAXED, __HIP_MEMORY_SCOPE_AGENT) < ep * nx)
        __builtin_amdgcn_s_sleep(2);
      __builtin_amdgcn_fence(__ATOMIC_ACQUIRE, "agent");   // ONE L2-inv / XCD
      __hip_atomic_store(&cnt[(8 + xcc) * 32], ep,
                         __ATOMIC_RELAXED, __HIP_MEMORY_SCOPE_AGENT);
    } else {
      while (__hip_atomic_load(&cnt[(8 + xcc) * 32],
                               __ATOMIC_RELAXED, __HIP_MEMORY_SCOPE_AGENT) < ep)
        __builtin_amdgcn_s_sleep(2);
      asm volatile("buffer_inv sc0\n\ts_waitcnt vmcnt(0)" ::: "memory");
    }
  }
  __syncthreads();
}

__device__ void transp(const float* __restrict__ src, float* __restrict__ dst,
                       int R, int Cn, float* sm) {
  const int tr_ = (R + 31) >> 5, tc_ = (Cn + 31) >> 5;
  for (int t = blockIdx.x; t < tr_ * tc_; t += gridDim.x) {
    const int r0 = (t / tc_) << 5, c0 = (t % tc_) << 5;
    __syncthreads();
    for (int e = threadIdx.x; e < 1024; e += NT) {
      const int rr = e >> 5, cc = e & 31, r = r0 + rr, c = c0 + cc;
      sm[rr * 33 + cc] = (r < R && c < Cn) ? src[(size_t)r * Cn + c] : 0.0f;
    }
    __syncthreads();
    for (int e = threadIdx.x; e < 1024; e += NT) {
      const int cc = e >> 5, rr = e & 31, r = r0 + rr, c = c0 + cc;
      if (r < R && c < Cn) dst[(size_t)c * R + r] = sm[rr * 33 + cc];
    }
  }
}

} // namespace

extern "C" __global__ __launch_bounds__(NT, 1)
void srnn(const float* __restrict__ data, const float* __restrict__ W_ih,
          const float* __restrict__ W_hh, const float* __restrict__ b_ih,
          const float* __restrict__ b_hh, const float* __restrict__ Wa,
          const float* __restrict__ ba, const float* __restrict__ W1,
          const float* __restrict__ b1, const float* __restrict__ W2,
          const float* __restrict__ Wout, const float* __restrict__ bout,
          float* __restrict__ out, float* __restrict__ ws)
{
  __shared__ __align__(16) float wlds[LD_TOT];   // 155,520 B persistent weights
  __shared__ double smd[528];                    // 4,224 B scratch (1056 floats)
  __shared__ unsigned s_xcc, s_xcnt, s_nx;
  float* smf = (float*)smd;
  unsigned* cnt = (unsigned*)ws;
  float* res   = ws + OF_RES;
  float* WihT  = ws + OF_WIT;
  float* WhhT  = ws + OF_WHT;
  float* WoutT = ws + OF_WOT;
  double* wd   = (double*)(ws + FLT_END);
  double* st2  = wd + D_ST;
  double* ctxD = wd + D_CTX;
  double* angD = wd + D_ANG;
  double* posD = wd + D_POS;
  double* dstD = wd + D_DST;                     // [2][B][L][3]
  double* Gd   = wd + D_G;
  double* wAr  = wd + D_W;
  double* wT   = wd + D_WT;                      // [B][HD][L]
  double* pND  = wd + D_PN;

  const int bid = blockIdx.x, tid = threadIdx.x;
  const int wid = tid >> 6, lane = tid & 63;
  unsigned ep = 0;

  // ---- XCD discovery (m09) ----
  if (tid == 0) {
    unsigned x;
    asm volatile("s_getreg_b32 %0, hwreg(HW_REG_XCC_ID)" : "=s"(x));
    x &= 7u;
    s_xcc = x;
    __hip_atomic_fetch_add(&cnt[(17 + x) * 32], 1u,
                           __ATOMIC_RELAXED, __HIP_MEMORY_SCOPE_AGENT);
  }

  // ================= init (covered by fenced gbar_init) =================
  for (int i = bid * NT + tid; i < (int)(D_ANG - D_ST); i += NB * NT)
    wd[i] = 0.0;                                 // state dbuf + ctx = 0
  {
    const int i = bid * NT + tid;                // B*L*A == NB*NT
    const int a = i & (A_ - 1);
    const int bj = i >> 7;
    double acc = (double)b1[a];
    const float* dr = data + (size_t)bj * IN_;
    #pragma unroll 8
    for (int k = 0; k < IN_; ++k)
      acc = fma((double)dr[k], (double)W1[(size_t)(H_ + k) * A_ + a], acc);
    Gd[i] = acc;
  }
  transp(W_ih, WihT, KX_, 3 * H_, smf);          // coalesced staging (r4-proven)
  transp(W_hh, WhhT, H_, 3 * H_, smf);
  transp(Wout, WoutT, KO_, C_, smf);
  gbar_init(cnt);

  // ---- XCD census ----
  if (tid == 0) {
    unsigned n = 0;
    for (int k = 0; k < 8; ++k)
      n += (__hip_atomic_load(&cnt[(17 + k) * 32],
                              __ATOMIC_RELAXED, __HIP_MEMORY_SCOPE_AGENT) > 0u);
    s_nx = n;
    s_xcnt = __hip_atomic_load(&cnt[(17 + s_xcc) * 32],
                               __ATOMIC_RELAXED, __HIP_MEMORY_SCOPE_AGENT);
  }

  // ---- persistent LDS weight slices (coalesced float4 from transposed) ----
  if (bid < 160) {
    for (int rg = 0; rg < 15; ++rg) {            // ih rows: 5 neurons x 3 gates
      const int s = rg / 3, g = rg % 3;
      const int i = bid * 5 + s;
      const float4* src = reinterpret_cast<const float4*>(WihT + (size_t)(g * H_ + i) * KX_);
      float4* dst = reinterpret_cast<float4*>(&wlds[s * LD_NEUR + g * 864]);
      for (int k4 = tid; k4 < 216; k4 += NT) dst[k4] = src[k4];
    }
    for (int rg = 0; rg < 15; ++rg) {            // hh rows
      const int s = rg / 3, g = rg % 3;
      const int i = bid * 5 + s;
      const float4* src = reinterpret_cast<const float4*>(WhhT + (size_t)(g * H_ + i) * H_);
      float4* dst = reinterpret_cast<float4*>(&wlds[s * LD_NEUR + 2592 + g * 800]);
      for (int k4 = tid; k4 < 200; k4 += NT) dst[k4] = src[k4];
    }
    for (int cs = 0; cs < 2; ++cs) {             // 2 Wout cols
      const int c = bid * 2 + cs;
      const float4* src = reinterpret_cast<const float4*>(WoutT + (size_t)c * KO_);
      float4* dst = reinterpret_cast<float4*>(&wlds[LD_WOUT_A + cs * KO_]);
      for (int k4 = tid; k4 < 1740; k4 += NT) dst[k4] = src[k4];
    }
  } else {
    for (int cs = 0; cs < 5; ++cs) {             // 5 Wout cols
      const int c = 320 + (bid - 160) * 5 + cs;
      const float4* src = reinterpret_cast<const float4*>(WoutT + (size_t)c * KO_);
      float4* dst = reinterpret_cast<float4*>(&wlds[cs * KO_]);
      for (int k4 = tid; k4 < 1740; k4 += NT) dst[k4] = src[k4];
    }
  }
  __syncthreads();
  const unsigned xcc = s_xcc, xcnt = s_xcnt, nx = s_nx;

  // ================= 128 steps, 3 barriers each =================
  for (int idx = 0; idx < L_; ++idx) {
    const int rp = idx & 1;
    const double* sOld = st2 + (size_t)rp * B_ * H_;
    double* sNew = st2 + (size_t)(rp ^ 1) * B_ * H_;
    const double* dstR = dstD + (size_t)(idx & 1) * (B_ * L_ * 3);       // read
    double* dstW = dstD + (size_t)((idx + 1) & 1) * (B_ * L_ * 3);       // write

    // ---- P1: GRU (type-A waves 0..4) || e/logits/w (1024 waves) ----
    if (bid < 160 && wid < 5) {
      const int i = bid * 5 + wid;               // neuron
      const int b = lane >> 3, ks = lane & 7;
      const float4* wr4 = reinterpret_cast<const float4*>(&wlds[wid * LD_NEUR]);
      const float4* wz4 = reinterpret_cast<const float4*>(&wlds[wid * LD_NEUR + 864]);
      const float4* wn4 = reinterpret_cast<const float4*>(&wlds[wid * LD_NEUR + 1728]);
      const float4* dx4 = reinterpret_cast<const float4*>(data + ((size_t)b * L_ + idx) * IN_);
      const double* cx = ctxD + (size_t)b * C_;
      double axr = 0., axz = 0., axn = 0.;
      #pragma unroll
      for (int j = 0; j < 2; ++j) {
        const int q = ks + 8 * j;
        const float4 x4 = dx4[q];
        const float4 r4 = wr4[q], z4 = wz4[q], n4 = wn4[q];
        const double x0 = x4.x, x1 = x4.y, x2 = x4.z, x3 = x4.w;
        axr = fma((double)r4.x, x0, axr); axr = fma((double)r4.y, x1, axr);
        axr = fma((double)r4.z, x2, axr); axr = fma((double)r4.w, x3, axr);
        axz = fma((double)z4.x, x0, axz); axz = fma((double)z4.y, x1, axz);
        axz = fma((double)z4.z, x2, axz); axz = fma((double)z4.w, x3, axz);
        axn = fma((double)n4.x, x0, axn); axn = fma((double)n4.y, x1, axn);
        axn = fma((double)n4.z, x2, axn); axn = fma((double)n4.w, x3, axn);
      }
      #pragma unroll 5
      for (int j = 2; j < 27; ++j) {
        const int q = ks + 8 * j;
        const int e = 4 * q - 64;
        const double x0 = cx[e], x1 = cx[e + 1], x2 = cx[e + 2], x3 = cx[e + 3];
        const float4 r4 = wr4[q], z4 = wz4[q], n4 = wn4[q];
        axr = fma((double)r4.x, x0, axr); axr = fma((double)r4.y, x1, axr);
        axr = fma((double)r4.z, x2, axr); axr = fma((double)r4.w, x3, axr);
        axz = fma((double)z4.x, x0, axz); axz = fma((double)z4.y, x1, axz);
        axz = fma((double)z4.z, x2, axz); axz = fma((double)z4.w, x3, axz);
        axn = fma((double)n4.x, x0, axn); axn = fma((double)n4.y, x1, axn);
        axn = fma((double)n4.z, x2, axn); axn = fma((double)n4.w, x3, axn);
      }
      const float4* hr4 = reinterpret_cast<const float4*>(&wlds[wid * LD_NEUR + 2592]);
      const float4* hz4 = reinterpret_cast<const float4*>(&wlds[wid * LD_NEUR + 2592 + 800]);
      const float4* hn4 = reinterpret_cast<const float4*>(&wlds[wid * LD_NEUR + 2592 + 1600]);
      const double* sx = sOld + (size_t)b * H_;
      double ahr = 0., ahz = 0., ahn = 0.;
      #pragma unroll 5
      for (int j = 0; j < 25; ++j) {
        const int q = ks + 8 * j;
        const int e = 4 * q;
        const double s0 = sx[e], s1 = sx[e + 1], s2 = sx[e + 2], s3 = sx[e + 3];
        const float4 r4 = hr4[q], z4 = hz4[q], n4 = hn4[q];
        ahr = fma((double)r4.x, s0, ahr); ahr = fma((double)r4.y, s1, ahr);
        ahr = fma((double)r4.z, s2, ahr); ahr = fma((double)r4.w, s3, ahr);
        ahz = fma((double)z4.x, s0, ahz); ahz = fma((double)z4.y, s1, ahz);
        ahz = fma((double)z4.z, s2, ahz); ahz = fma((double)z4.w, s3, ahz);
        ahn = fma((double)n4.x, s0, ahn); ahn = fma((double)n4.y, s1, ahn);
        ahn = fma((double)n4.z, s2, ahn); ahn = fma((double)n4.w, s3, ahn);
      }
      #pragma unroll
      for (int off = 1; off < 8; off <<= 1) {
        axr += __shfl_xor(axr, off); axz += __shfl_xor(axz, off); axn += __shfl_xor(axn, off);
        ahr += __shfl_xor(ahr, off); ahz += __shfl_xor(ahz, off); ahn += __shfl_xor(ahn, off);
      }
      if (ks == 0) {
        const double xr = axr + (double)b_ih[i], xz = axz + (double)b_ih[H_ + i],
                     xn = axn + (double)b_ih[2 * H_ + i];
        const double hr = ahr + (double)b_hh[i], hz = ahz + (double)b_hh[H_ + i],
                     hn = ahn + (double)b_hh[2 * H_ + i];
        const double r = 1.0 / (1.0 + exp(-(xr + hr)));
        const double z = 1.0 / (1.0 + exp(-(xz + hz)));
        const double n = tanh(xn + r * hn);
        const double sn = (1.0 - z) * n + z * sOld[b * H_ + i];
        sNew[b * H_ + i] = sn;
        res[((size_t)b * L_ + idx) * H_ + i] = (float)sn;
      }
    } else {
      int tsk = -1;
      if (bid >= 160) tsk = (bid - 160) * 8 + wid;          // 0..767
      else tsk = 768 + bid * 3 + (wid - 5);                  // 768..1247
      if (tsk < 1024 && idx > 0) {
        const int b = tsk >> 7, j = tsk & (L_ - 1);
        if (j < idx) {                           // guard: skip future rows
          const size_t bj = (size_t)b * L_ + j;
          double e0 = Gd[bj * A_ + lane], e1 = Gd[bj * A_ + lane + 64];
          const double an0 = angD[bj * 3], an1 = angD[bj * 3 + 1], an2 = angD[bj * 3 + 2];
          const double dd0 = dstR[bj * 3], dd1 = dstR[bj * 3 + 1], dd2 = dstR[bj * 3 + 2];
          e0 = fma((double)W1[864 * A_ + lane], an0, e0);
          e0 = fma((double)W1[865 * A_ + lane], an1, e0);
          e0 = fma((double)W1[866 * A_ + lane], an2, e0);
          e0 = fma((double)W1[867 * A_ + lane], dd0, e0);
          e0 = fma((double)W1[868 * A_ + lane], dd1, e0);
          e0 = fma((double)W1[869 * A_ + lane], dd2, e0);
          e1 = fma((double)W1[864 * A_ + lane + 64], an0, e1);
          e1 = fma((double)W1[865 * A_ + lane + 64], an1, e1);
          e1 = fma((double)W1[866 * A_ + lane + 64], an2, e1);
          e1 = fma((double)W1[867 * A_ + lane + 64], dd0, e1);
          e1 = fma((double)W1[868 * A_ + lane + 64], dd1, e1);
          e1 = fma((double)W1[869 * A_ + lane + 64], dd2, e1);
          e0 = tanh(e0); e1 = tanh(e1);
          double lg[8];
          #pragma unroll
          for (int h = 0; h < 8; ++h) {
            double v = fma(e0, (double)W2[lane * 8 + h], e1 * (double)W2[(lane + 64) * 8 + h]);
            #pragma unroll
            for (int off = 1; off < 64; off <<= 1) v += __shfl_xor(v, off);
            lg[h] = v;
          }
          if (lane == 0) {
            const bool valid = (dd1 <= RAD_);
            double* wrow = wAr + bj * HD_;
            #pragma unroll
            for (int h = 0; h < 8; ++h) {
              const double wv = valid ? exp(lg[h]) : 0.0;
              wrow[h] = wv;
              wT[((size_t)b * HD_ + h) * L_ + j] = wv;   // transposed copy
            }
          }
        }
      }
    }
    gbarx(cnt, ep, xcc, xcnt, nx);

    // ---- P2: pooled (0..127) || G-update (128..135) || angle+pos+dist (136) ----
    if (bid < 128) {
      if (idx > 0) {
        const int b = bid >> 4, sl = bid & 15;
        if (tid < 8) {                           // zs per h, same order as before
          const double* wt = wT + ((size_t)b * HD_ + tid) * L_;
          double zs = 0.0;
          for (int j = 0; j < idx; ++j) zs += wt[j];
          smd[tid] = zs;
        }
        __syncthreads();
        const int f0 = sl * 55;
        const int fn = (F_ - f0 < 55) ? (F_ - f0) : 55;
        const int fl = tid >> 3, h = tid & 7;
        if (fl < fn) {
          const int f = f0 + fl;
          const float* fbf = nullptr; const double* fbd = nullptr; int strd = 0;
          if (f < H_)                { fbf = res  + f + (size_t)b * L_ * H_;               strd = H_;  }
          else if (f < H_ + IN_)     { fbf = data + (f - H_) + (size_t)b * L_ * IN_;       strd = IN_; }
          else if (f < H_ + IN_ + 3) { fbd = angD + (f - H_ - IN_) + (size_t)b * L_ * 3;   strd = 3;   }
          else                       { fbd = dstR + (f - H_ - IN_ - 3) + (size_t)b * L_ * 3; strd = 3; }
          const double* wt = wT + ((size_t)b * HD_ + h) * L_;
          double acc = 0.0;
          #pragma unroll 4
          for (int j = 0; j < idx; ++j) {
            const double fv = fbf ? (double)fbf[(size_t)j * strd] : fbd[(size_t)j * strd];
            acc = fma(wt[j], fv, acc);
          }
          pND[(size_t)b * KO_ + (size_t)h * F_ + f] = acc / smd[h];
        }
      }
    } else if (bid < 136) {
      const int b = bid - 128;                   // G-row update for step idx
      const int a = tid & (A_ - 1), ksl = tid >> 7;
      const double* sr = sNew + (size_t)b * H_;
      const int i0 = ksl * 200;
      double p = 0.0;
      #pragma unroll 4
      for (int k = 0; k < 200; ++k)
        p = fma(sr[i0 + k], (double)W1[(size_t)(i0 + k) * A_ + a], p);
      smd[tid] = p;
      __syncthreads();
      if (tid < 128)
        Gd[((size_t)b * L_ + idx) * A_ + tid] +=
            smd[tid] + smd[128 + tid] + smd[256 + tid] + smd[384 + tid];
    } else if (bid == 136) {
      const int b7 = tid / 48, rem = tid % 48, t3 = rem / 16, ksl = rem & 15;
      if (tid < 384) {
        const double* sr = sNew + (size_t)b7 * H_;
        const int i0 = ksl * 50;
        double p = 0.0;
        for (int k = 0; k < 50; ++k)
          p = fma(sr[i0 + k], (double)Wa[(i0 + k) * 3 + t3], p);
        smd[tid] = p;
      }
      __syncthreads();
      if (tid < 24) {
        const int b2 = tid / 3, t4 = tid % 3;
        double s = (double)ba[t4];
        for (int u = 0; u < 16; ++u) s += smd[b2 * 48 + t4 * 16 + u];
        smd[384 + tid] = s;
        angD[((size_t)b2 * L_ + idx) * 3 + t4] = s;
        out[(size_t)B_ * L_ * 9 + ((size_t)b2 * L_ + idx) * 3 + t4] = (float)s;
      }
      __syncthreads();
      if (tid < 24) {
        const int b2 = tid / 3, t4 = tid % 3;
        const double a = smd[384 + b2 * 3 + t4];
        const double asum = smd[384 + b2 * 3] + smd[384 + b2 * 3 + 1] + smd[384 + b2 * 3 + 2];
        const double sa = sin(a), ca = cos(a), cs = cos(asum), ss = sin(asum);
        double px = 0., py = 0., pz = 0.;
        if (idx > 0) {
          const double* pr = posD + ((size_t)b2 * L_ + idx - 1) * 9 + t4 * 3;
          px = pr[0]; py = pr[1]; pz = pr[2];
        }
        px = fma(BOND_, ca, px);
        py = fma(BOND_, sa * cs, py);
        pz = fma(BOND_, sa * ss, pz);
        double* pw = posD + ((size_t)b2 * L_ + idx) * 9 + t4 * 3;
        pw[0] = px; pw[1] = py; pw[2] = pz;
        float* ow = out + ((size_t)b2 * L_ + idx) * 9 + t4 * 3;
        ow[0] = (float)px; ow[1] = (float)py; ow[2] = (float)pz;
      }
      __syncthreads();
      if (idx < L_ - 1) {                        // dist rows j<=idx vs pos[idx]
        for (int u = tid; u < 4096; u += NT) {
          const int b = u >> 9, rem2 = u & 511;
          const int j = rem2 >> 2, t6 = rem2 & 3;
          if (t6 < 3 && j <= idx) {
            const double* pa = posD + ((size_t)b * L_ + idx) * 9 + t6 * 3;
            const double* pb = posD + ((size_t)b * L_ + j) * 9 + t6 * 3;
            const double dx = pa[0] - pb[0], dy = pa[1] - pb[1], dz = pa[2] - pb[2];
            dstW[((size_t)b * L_ + j) * 3 + t6] =
                sqrt(fma(dx, dx, fma(dy, dy, fma(dz, dz, 1e-12))));
          }
        }
      }
    }
    gbarx(cnt, ep, xcc, xcnt, nx);

    // ---- P3: ctx = pooledN @ Wout(LDS cols) + bout ----
    if (idx < L_ - 1) {
      const int ntask = (bid < 160) ? 2 : 5;
      for (int u = 0; u < ntask; ++u) {
        const int t = wid + 8 * u;
        const int cs = t >> 3, b = t & 7;
        const int c = (bid < 160) ? (bid * 2 + cs) : (320 + (bid - 160) * 5 + cs);
        const int cbase = ((bid < 160) ? LD_WOUT_A : 0) + cs * KO_;
        double acc = 0.0;
        if (idx > 0) {
          const double* pr = pND + (size_t)b * KO_;
          #pragma unroll 4
          for (int m = 0; m < 27; ++m) {         // q max 1727 < 1740: no guard
            const int q = lane + 64 * m;
            const float4 w4 = *reinterpret_cast<const float4*>(&wlds[cbase + 4 * q]);
            const int e = 4 * q;
            acc = fma((double)w4.x, pr[e],     acc);
            acc = fma((double)w4.y, pr[e + 1], acc);
            acc = fma((double)w4.z, pr[e + 2], acc);
            acc = fma((double)w4.w, pr[e + 3], acc);
          }
          {                                       // m = 27, guarded tail
            const int q = lane + 64 * 27;
            if (q < 1740) {
              const float4 w4 = *reinterpret_cast<const float4*>(&wlds[cbase + 4 * q]);
              const int e = 4 * q;
              acc = fma((double)w4.x, pr[e],     acc);
              acc = fma((double)w4.y, pr[e + 1], acc);
              acc = fma((double)w4.z, pr[e + 2], acc);
              acc = fma((double)w4.w, pr[e + 3], acc);
            }
          }
          #pragma unroll
          for (int off = 1; off < 64; off <<= 1) acc += __shfl_xor(acc, off);
        }
        if (lane == 0)
          ctxD[b * C_ + c] = (idx > 0) ? (acc + (double)bout[c]) : 0.0;
      }
    }
    gbarx(cnt, ep, xcc, xcnt, nx);
  }
}

extern "C" void kernel_launch(void* const* d_in, const int* in_sizes, int n_in,
                              void* d_out, int out_size, void* d_ws, size_t ws_size,
                              hipStream_t stream) {
  (void)in_sizes; (void)n_in; (void)out_size;
  if (ws_size < WS_BYTES) return;
  const float* data = (const float*)d_in[0];
  const float* W_ih = (const float*)d_in[1];
  const float* W_hh = (const float*)d_in[2];
  const float* b_ih = (const float*)d_in[3];
  const float* b_hh = (const float*)d_in[4];
  const float* Wa   = (const float*)d_in[5];
  const float* ba   = (const float*)d_in[6];
  const float* W1   = (const float*)d_in[7];
  const float* b1   = (const float*)d_in[8];
  const float* W2   = (const float*)d_in[9];
  const float* Wout = (const float*)d_in[10];
  const float* bout = (const float*)d_in[11];
  hipMemsetAsync(d_ws, 0, 8192, stream);         // reset barrier state (replay-safe)
  srnn<<<dim3(NB), dim3(NT), 0, stream>>>(data, W_ih, W_hh, b_ih, b_hh, Wa, ba,
                                          W1, b1, W2, Wout, bout,
                                          (float*)d_out, (float*)d_ws);
}